// Round 4
// baseline (186.473 us; speedup 1.0000x reference)
//
#include <hip/hip_runtime.h>

#define HH   48
#define WW   48
#define NPIX 2304
#define CIN  32
#define COUT 64
#define KNB  29
#define FCO  16
#define NEVAL (KNB * 16)   // 464 evals per pixel

__device__ __forceinline__ float swish_f(float x) {
    // x * sigmoid(x); v_rcp_f32 instead of the 10-inst exact-division sequence
    return x * __builtin_amdgcn_rcpf(1.0f + __expf(-x));
}

// f64 Rodrigues matching reference so3_exp
__device__ __forceinline__ void so3_exp_d(double wx, double wy, double wz, double R[9]) {
    double n  = sqrt(wx * wx + wy * wy + wz * wz);
    double th = fmax(n, 1e-7);
    double kx = wx / th, ky = wy / th, kz = wz / th;
    double s = sin(th), c = cos(th);
    double omc = 1.0 - c;
    R[0] = 1.0 + omc * (kx * kx - 1.0);
    R[1] = -s * kz + omc * kx * ky;
    R[2] =  s * ky + omc * kx * kz;
    R[3] =  s * kz + omc * kx * ky;
    R[4] = 1.0 + omc * (ky * ky - 1.0);
    R[5] = -s * kx + omc * ky * kz;
    R[6] = -s * ky + omc * kz * kx;
    R[7] =  s * kx + omc * kz * ky;
    R[8] = 1.0 + omc * (kz * kz - 1.0);
}

// f64 fisheye lift rotation Rp for pixel p (matches reference _lift_log)
__device__ __forceinline__ void compute_Rp_d(int p, double R[9]) {
    int ui = p % WW, vi = p / WW;
    double dx = (double)ui - 23.5;
    double dy = (double)vi - 23.5;
    double r  = sqrt(dx * dx + dy * dy);
    const double FOCAL = 48.0 / 3.14159265358979323846;
    double theta = r / FOCAL;
    double rs = fmax(r, 1e-7);
    double st = sin(theta);
    double rayx = st * dx / rs;
    double rayy = st * dy / rs;
    double rayz = cos(theta);
    double pz  = fmin(fmax(rayz, -1.0 + 1e-6), 1.0 - 1e-6);
    double ang = acos(pz);
    double ax = -rayy, ay = rayx;               // axis (z comp = 0)
    double an = fmax(sqrt(ax * ax + ay * ay), 1e-7);
    ax /= an; ay /= an;
    so3_exp_d(ax * ang, ay * ang, 0.0, R);
}

__global__ __launch_bounds__(512, 2)
void fisheye_kernel(const float* __restrict__ x, const int* __restrict__ nbr,
                    const float* __restrict__ W1, const float* __restrict__ b1,
                    const float* __restrict__ W2, const float* __restrict__ b2,
                    const float* __restrict__ W3, const float* __restrict__ b3,
                    const float* __restrict__ Wl, const float* __restrict__ bl,
                    float* __restrict__ out)
{
    __shared__ double s_Rq[9];
    __shared__ double s_Rn[KNB][9];
    __shared__ double s_Rrel[KNB][9];          // Rn^T * Rq
    __shared__ int    s_pj[KNB];
    __shared__ int    s_valid[KNB];
    __shared__ float  s_wts[NEVAL * 17];       // padded stride 17
    __shared__ float  s_S[KNB * FCO];
    __shared__ float  s_xv[2 * CIN * KNB];
    __shared__ float  s_T[2 * CIN * FCO];

    const int p = blockIdx.x;
    const int t = threadIdx.x;

    // ---- Phase A: lift rotations (f64) ----
    if (t < KNB) {
        int idx = nbr[p * KNB + t];
        int pj = max(idx, 0);
        s_pj[t] = pj;
        s_valid[t] = (idx >= 0) ? 1 : 0;
        double R[9];
        compute_Rp_d(pj, R);
        #pragma unroll
        for (int e = 0; e < 9; ++e) s_Rn[t][e] = R[e];
    } else if (t == KNB) {
        double R[9];
        compute_Rp_d(p, R);
        #pragma unroll
        for (int e = 0; e < 9; ++e) s_Rq[e] = R[e];
    }
    __syncthreads();
    if (t < KNB) {
        // Rrel = Rn^T * Rq
        #pragma unroll
        for (int i = 0; i < 3; ++i)
            #pragma unroll
            for (int jj = 0; jj < 3; ++jj) {
                double acc = 0.0;
                #pragma unroll
                for (int kk = 0; kk < 3; ++kk)
                    acc += s_Rn[t][kk * 3 + i] * s_Rq[kk * 3 + jj];
                s_Rrel[t][i * 3 + jj] = acc;
            }
    }
    __syncthreads();

    // ---- Phase B: 464 evals; sign-permutation C + f64 log + streaming f32 MLP ----
    if (t < NEVAL) {
        int j  = t >> 4;
        int u  = t & 15;
        int l2 = u >> 2;   // neighbor-side lift
        int l1 = u & 3;    // query-side lift
        float* wdst = &s_wts[t * 17];
        if (!s_valid[j]) {
            #pragma unroll
            for (int f = 0; f < FCO; ++f) wdst[f] = 0.f;
        } else {
            // Effective lift E = Rp*Rz(l) for l in {0,1,3}; E = I for l==2
            // (reference's exp(log(.)) roundtrip collapses exact-pi l==2 to I).
            // C = E_b^T * E_a, built by sign/column permutation (90-deg Rz exact).
            float ab0, ab1, ab2;
            if (l1 == 2 && l2 == 2) {
                ab0 = ab1 = ab2 = 0.f;
            } else {
                double M[9];
                if (l1 != 2) {
                    const double* base = (l2 == 2) ? s_Rq : s_Rrel[j];
                    // M = base * Rz(l1): col-mix
                    if (l1 == 0) {
                        #pragma unroll
                        for (int i = 0; i < 3; ++i) {
                            M[i * 3 + 0] = base[i * 3 + 0];
                            M[i * 3 + 1] = base[i * 3 + 1];
                            M[i * 3 + 2] = base[i * 3 + 2];
                        }
                    } else if (l1 == 1) {
                        #pragma unroll
                        for (int i = 0; i < 3; ++i) {
                            M[i * 3 + 0] =  base[i * 3 + 1];
                            M[i * 3 + 1] = -base[i * 3 + 0];
                            M[i * 3 + 2] =  base[i * 3 + 2];
                        }
                    } else { // l1 == 3
                        #pragma unroll
                        for (int i = 0; i < 3; ++i) {
                            M[i * 3 + 0] = -base[i * 3 + 1];
                            M[i * 3 + 1] =  base[i * 3 + 0];
                            M[i * 3 + 2] =  base[i * 3 + 2];
                        }
                    }
                    if (l2 == 1) {        // rows: (r0,r1) <- (r1,-r0)
                        #pragma unroll
                        for (int jj = 0; jj < 3; ++jj) {
                            double r0 = M[0 * 3 + jj], r1 = M[1 * 3 + jj];
                            M[0 * 3 + jj] =  r1;
                            M[1 * 3 + jj] = -r0;
                        }
                    } else if (l2 == 3) { // rows: (r0,r1) <- (-r1,r0)
                        #pragma unroll
                        for (int jj = 0; jj < 3; ++jj) {
                            double r0 = M[0 * 3 + jj], r1 = M[1 * 3 + jj];
                            M[0 * 3 + jj] = -r1;
                            M[1 * 3 + jj] =  r0;
                        }
                    }
                } else {
                    // l1 == 2, l2 != 2: C = Rz(l2)^T * Rn^T
                    double Tm[9];
                    #pragma unroll
                    for (int i = 0; i < 3; ++i)
                        #pragma unroll
                        for (int jj = 0; jj < 3; ++jj)
                            Tm[i * 3 + jj] = s_Rn[j][jj * 3 + i];
                    if (l2 == 0) {
                        #pragma unroll
                        for (int e = 0; e < 9; ++e) M[e] = Tm[e];
                    } else if (l2 == 1) {
                        #pragma unroll
                        for (int jj = 0; jj < 3; ++jj) {
                            M[0 * 3 + jj] =  Tm[1 * 3 + jj];
                            M[1 * 3 + jj] = -Tm[0 * 3 + jj];
                            M[2 * 3 + jj] =  Tm[2 * 3 + jj];
                        }
                    } else { // l2 == 3
                        #pragma unroll
                        for (int jj = 0; jj < 3; ++jj) {
                            M[0 * 3 + jj] = -Tm[1 * 3 + jj];
                            M[1 * 3 + jj] =  Tm[0 * 3 + jj];
                            M[2 * 3 + jj] =  Tm[2 * 3 + jj];
                        }
                    }
                }
                // so3_log (reference formula incl. clipping), f64
                double tr   = M[0] + M[4] + M[8];
                double cosv = fmin(fmax((tr - 1.0) * 0.5, -1.0 + 1e-6), 1.0 - 1e-6);
                double th   = acos(cosv);
                double sv   = sqrt((1.0 - cosv) * (1.0 + cosv));  // == sin(th)
                double fac  = th / (2.0 * sv);
                ab0 = (float)((M[7] - M[5]) * fac);
                ab1 = (float)((M[2] - M[6]) * fac);
                ab2 = (float)((M[3] - M[1]) * fac);
            }
            // Streaming MLP 3->32->32->16 (f32); peak live ~52 VGPRs.
            float acc2[32];
            #pragma unroll
            for (int o = 0; o < 32; ++o) acc2[o] = b2[o];
            #pragma unroll
            for (int i = 0; i < 32; ++i) {
                float h = swish_f(b1[i] + ab0 * W1[i] + ab1 * W1[32 + i] + ab2 * W1[64 + i]);
                #pragma unroll
                for (int o = 0; o < 32; ++o) acc2[o] += h * W2[i * 32 + o];
            }
            float acc3[FCO];
            #pragma unroll
            for (int f = 0; f < FCO; ++f) acc3[f] = b3[f];
            #pragma unroll
            for (int o = 0; o < 32; ++o) {
                float h = swish_f(acc2[o]);
                #pragma unroll
                for (int f = 0; f < FCO; ++f) acc3[f] += h * W3[o * FCO + f];
            }
            #pragma unroll
            for (int f = 0; f < FCO; ++f) wdst[f] = swish_f(acc3[f]);
        }
    } else {
        // threads 464..511 stage x values for this pixel's neighborhood
        for (int e = t - NEVAL; e < 2 * CIN * KNB; e += (512 - NEVAL)) {
            int bb  = e / (CIN * KNB);
            int rem = e - bb * (CIN * KNB);
            int c   = rem / KNB;
            int j   = rem - c * KNB;
            s_xv[e] = x[bb * (CIN * NPIX) + c * NPIX + s_pj[j]];
        }
    }
    __syncthreads();

    // ---- Phase C: S[j][f] = (1/L) * sum over (l1,l2) of wts ----
    if (t < NEVAL) {
        int j = t >> 4, f = t & 15;
        float acc = 0.f;
        #pragma unroll
        for (int u = 0; u < 16; ++u)
            acc += s_wts[(j * 16 + u) * 17 + f];
        s_S[j * FCO + f] = acc * 0.25f;
    }
    __syncthreads();

    // ---- Phase D: T[b][c][f] = sum_j xv[b][c][j] * S[j][f] ----
    for (int tt = t; tt < 2 * CIN * FCO; tt += 512) {
        int bb = tt >> 9;
        int c  = (tt >> 4) & 31;
        int f  = tt & 15;
        float acc = 0.f;
        #pragma unroll
        for (int j = 0; j < KNB; ++j)
            acc += s_xv[(bb * CIN + c) * KNB + j] * s_S[j * FCO + f];
        s_T[tt] = acc;
    }
    __syncthreads();

    // ---- Phase E: out[b,co,p] = sum_cf T[b][cf] * Wl[cf][co] + bl[co] ----
    if (t < 2 * COUT) {
        int bb = t >> 6, co = t & 63;
        float acc = bl[co];
        const float* Tb = &s_T[bb * (CIN * FCO)];
        #pragma unroll 8
        for (int cf = 0; cf < CIN * FCO; ++cf)
            acc += Tb[cf] * Wl[cf * COUT + co];
        out[bb * (COUT * NPIX) + co * NPIX + p] = acc;
    }
}

extern "C" void kernel_launch(void* const* d_in, const int* in_sizes, int n_in,
                              void* d_out, int out_size, void* d_ws, size_t ws_size,
                              hipStream_t stream) {
    const float* x  = (const float*)d_in[0];
    const int* nbr  = (const int*)d_in[1];
    const float* W1 = (const float*)d_in[2];
    const float* b1 = (const float*)d_in[3];
    const float* W2 = (const float*)d_in[4];
    const float* b2 = (const float*)d_in[5];
    const float* W3 = (const float*)d_in[6];
    const float* b3 = (const float*)d_in[7];
    const float* Wl = (const float*)d_in[8];
    const float* bl = (const float*)d_in[9];
    float* out = (float*)d_out;

    hipLaunchKernelGGL(fisheye_kernel, dim3(NPIX), dim3(512), 0, stream,
                       x, nbr, W1, b1, W2, b2, W3, b3, Wl, bl, out);
}

// Round 5
// 157.028 us; speedup vs baseline: 1.1875x; 1.1875x over previous
//
#include <hip/hip_runtime.h>

#define WW   48
#define NPIX 2304
#define CIN  32
#define COUT 64
#define KNB  29
#define FCO  16
#define NGEN (KNB * 9)     // 261 generic evals per pixel

// workspace layout (bytes); total 1,050,688 B
#define WS_RP64 0                        // 2304*9 double = 165888
#define WS_EG   165888                   // 2304*6*16 f32 = 884736  ([pix][which][f], which 0-2 = MLP(+a_l), 3-5 = MLP(-a_l), l in {0,1,3})
#define WS_M0   (165888 + 884736)        // 16 f32 = MLP(0)

__device__ __forceinline__ float swish_f(float x) {
    return x / (1.0f + __expf(-x));
}

// f64 Rodrigues matching reference so3_exp
__device__ __forceinline__ void so3_exp_d(double wx, double wy, double wz, double R[9]) {
    double n  = sqrt(wx * wx + wy * wy + wz * wz);
    double th = fmax(n, 1e-7);
    double kx = wx / th, ky = wy / th, kz = wz / th;
    double s = sin(th), c = cos(th);
    double omc = 1.0 - c;
    R[0] = 1.0 + omc * (kx * kx - 1.0);
    R[1] = -s * kz + omc * kx * ky;
    R[2] =  s * ky + omc * kx * kz;
    R[3] =  s * kz + omc * kx * ky;
    R[4] = 1.0 + omc * (ky * ky - 1.0);
    R[5] = -s * kx + omc * ky * kz;
    R[6] = -s * ky + omc * kz * kx;
    R[7] =  s * kx + omc * kz * ky;
    R[8] = 1.0 + omc * (kz * kz - 1.0);
}

// f64 fisheye lift rotation Rp for pixel p (matches reference _lift_log)
__device__ __forceinline__ void compute_Rp_d(int p, double R[9]) {
    int ui = p % WW, vi = p / WW;
    double dx = (double)ui - 23.5;
    double dy = (double)vi - 23.5;
    double r  = sqrt(dx * dx + dy * dy);
    const double FOCAL = 48.0 / 3.14159265358979323846;
    double theta = r / FOCAL;
    double rs = fmax(r, 1e-7);
    double st = sin(theta);
    double rayx = st * dx / rs;
    double rayy = st * dy / rs;
    double rayz = cos(theta);
    double pz  = fmin(fmax(rayz, -1.0 + 1e-6), 1.0 - 1e-6);
    double ang = acos(pz);
    double ax = -rayy, ay = rayx;
    double an = fmax(sqrt(ax * ax + ay * ay), 1e-7);
    ax /= an; ay /= an;
    so3_exp_d(ax * ang, ay * ang, 0.0, R);
}

// streaming f32 MLP 3->32->32->16
__device__ __forceinline__ void mlp_eval(float ab0, float ab1, float ab2,
    const float* __restrict__ W1, const float* __restrict__ b1,
    const float* __restrict__ W2, const float* __restrict__ b2,
    const float* __restrict__ W3, const float* __restrict__ b3,
    float* dst) {
    float acc2[32];
    #pragma unroll
    for (int o = 0; o < 32; ++o) acc2[o] = b2[o];
    #pragma unroll
    for (int i = 0; i < 32; ++i) {
        float h = swish_f(b1[i] + ab0 * W1[i] + ab1 * W1[32 + i] + ab2 * W1[64 + i]);
        #pragma unroll
        for (int o = 0; o < 32; ++o) acc2[o] += h * W2[i * 32 + o];
    }
    float acc3[FCO];
    #pragma unroll
    for (int f = 0; f < FCO; ++f) acc3[f] = b3[f];
    #pragma unroll
    for (int o = 0; o < 32; ++o) {
        float h = swish_f(acc2[o]);
        #pragma unroll
        for (int f = 0; f < FCO; ++f) acc3[f] += h * W3[o * FCO + f];
    }
    #pragma unroll
    for (int f = 0; f < FCO; ++f) dst[f] = swish_f(acc3[f]);
}

// so3_log of M (f64, reference formula incl. clipping) -> v
__device__ __forceinline__ void so3_log_d(const double M[9], double v[3]) {
    double tr   = M[0] + M[4] + M[8];
    double cosv = fmin(fmax((tr - 1.0) * 0.5, -1.0 + 1e-6), 1.0 - 1e-6);
    double th   = acos(cosv);
    double sv   = sqrt((1.0 - cosv) * (1.0 + cosv));   // == sin(th)
    double fac  = th / (2.0 * sv);
    v[0] = (M[7] - M[5]) * fac;
    v[1] = (M[2] - M[6]) * fac;
    v[2] = (M[3] - M[1]) * fac;
}

// ---------------- kernel 1: per-pixel prep ----------------
// g in [0, 2304*6): pixel = g/6, which = g%6. which<3 -> e = MLP(+a[p,l]),
// which>=3 -> g = MLP(-a[p,l]), l = {0,1,3}[which%3]. g==2304*6 -> MLP(0).
__global__ __launch_bounds__(256)
void prep_kernel(const float* __restrict__ W1, const float* __restrict__ b1,
                 const float* __restrict__ W2, const float* __restrict__ b2,
                 const float* __restrict__ W3, const float* __restrict__ b3,
                 double* __restrict__ rp64, float* __restrict__ eg,
                 float* __restrict__ m0v) {
    int g = blockIdx.x * 256 + threadIdx.x;
    if (g > NPIX * 6) return;
    if (g == NPIX * 6) {
        float o[16];
        mlp_eval(0.f, 0.f, 0.f, W1, b1, W2, b2, W3, b3, o);
        #pragma unroll
        for (int f = 0; f < FCO; ++f) m0v[f] = o[f];
        return;
    }
    int pix = g / 6, which = g - pix * 6;
    double R[9];
    compute_Rp_d(pix, R);
    if (which == 0) {
        #pragma unroll
        for (int e = 0; e < 9; ++e) rp64[pix * 9 + e] = R[e];
    }
    int m = (which < 3) ? which : (which - 3);
    int l = m + (m >> 1);                       // 0,1,3
    double c = (l == 0) ? 1.0 : 0.0;
    double s = (l == 1) ? 1.0 : ((l == 3) ? -1.0 : 0.0);
    // M = R * Rz(alpha_l)  (col mix)
    double M[9];
    #pragma unroll
    for (int i = 0; i < 3; ++i) {
        M[i * 3 + 0] =  R[i * 3 + 0] * c + R[i * 3 + 1] * s;
        M[i * 3 + 1] = -R[i * 3 + 0] * s + R[i * 3 + 1] * c;
        M[i * 3 + 2] =  R[i * 3 + 2];
    }
    double v[3];
    so3_log_d(M, v);
    float sg = (which < 3) ? 1.f : -1.f;
    mlp_eval(sg * (float)v[0], sg * (float)v[1], sg * (float)v[2],
             W1, b1, W2, b2, W3, b3, eg + g * FCO);
}

// ---------------- kernel 2: main ----------------
__global__ __launch_bounds__(320, 4)
void main_kernel(const float* __restrict__ x, const int* __restrict__ nbr,
                 const float* __restrict__ W1, const float* __restrict__ b1,
                 const float* __restrict__ W2, const float* __restrict__ b2,
                 const float* __restrict__ W3, const float* __restrict__ b3,
                 const float* __restrict__ Wl, const float* __restrict__ bl,
                 const double* __restrict__ rp64, const float* __restrict__ eg,
                 const float* __restrict__ m0v, float* __restrict__ out) {
    __shared__ double sRq[9];
    __shared__ double sX[KNB][9];       // X_j = Rn^T * Rq (f64)
    __shared__ float  sv[KNB][4][3];    // v_d = log(X * Rz(d)), f32
    __shared__ int    spj[KNB];
    __shared__ int    sval[KNB];
    __shared__ float  sE[FCO];          // sum_l1 MLP(a[p,l1]) + MLP(0)
    __shared__ float  swts[NGEN][17];   // generic eval outputs (pad 17)
    __shared__ float  sS[KNB][FCO];
    __shared__ float  sxv[2][CIN][KNB];
    __shared__ float  sT[2][CIN][FCO];
    __shared__ float  spp[256];

    const int p = blockIdx.x;
    const int t = threadIdx.x;

    // ---- P0: neighbor idx + Rq load ----
    if (t < KNB) {
        int idx = nbr[p * KNB + t];
        spj[t]  = max(idx, 0);
        sval[t] = (idx >= 0) ? 1 : 0;
    } else if (t >= 32 && t < 41) {
        sRq[t - 32] = rp64[p * 9 + (t - 32)];
    }
    __syncthreads();

    // ---- P1: X_j (f64) | x staging | E vector ----
    if (t < KNB) {
        double Rn[9];
        const double* src = rp64 + spj[t] * 9;
        #pragma unroll
        for (int e = 0; e < 9; ++e) Rn[e] = src[e];
        #pragma unroll
        for (int i = 0; i < 3; ++i)
            #pragma unroll
            for (int jj = 0; jj < 3; ++jj) {
                double acc = 0.0;
                #pragma unroll
                for (int kk = 0; kk < 3; ++kk)
                    acc += Rn[kk * 3 + i] * sRq[kk * 3 + jj];
                sX[t][i * 3 + jj] = acc;
            }
    } else if (t >= 64 && t < 256) {
        for (int e = t - 64; e < 2 * CIN * KNB; e += 192) {
            int bb = e / (CIN * KNB);
            int r  = e - bb * (CIN * KNB);
            int c  = r / KNB;
            int j  = r - c * KNB;
            sxv[bb][c][j] = x[bb * (CIN * NPIX) + c * NPIX + spj[j]];
        }
    } else if (t >= 304) {
        int f = t - 304;
        sE[f] = eg[(p * 6 + 0) * FCO + f] + eg[(p * 6 + 1) * FCO + f]
              + eg[(p * 6 + 2) * FCO + f] + m0v[f];
    }
    __syncthreads();

    // ---- P2: v_d = log(X * Rz(d)) (f64 -> f32) ----
    if (t < KNB * 4) {
        int j = t >> 2, d = t & 3;
        double c = (d == 0) ? 1.0 : ((d == 2) ? -1.0 : 0.0);
        double s = (d == 1) ? 1.0 : ((d == 3) ? -1.0 : 0.0);
        const double* X = sX[j];
        double M0 =  X[0] * c + X[1] * s;
        double M1 = -X[0] * s + X[1] * c;
        double M2 =  X[2];
        double M3 =  X[3] * c + X[4] * s;
        double M4 = -X[3] * s + X[4] * c;
        double M5 =  X[5];
        double M6 =  X[6] * c + X[7] * s;
        double M7 = -X[6] * s + X[7] * c;
        double M8 =  X[8];
        double tr   = M0 + M4 + M8;
        double cosv = fmin(fmax((tr - 1.0) * 0.5, -1.0 + 1e-6), 1.0 - 1e-6);
        double th   = acos(cosv);
        double svv  = sqrt((1.0 - cosv) * (1.0 + cosv));
        double fac  = th / (2.0 * svv);
        sv[j][d][0] = (float)((M7 - M5) * fac);
        sv[j][d][1] = (float)((M2 - M6) * fac);
        sv[j][d][2] = (float)((M3 - M1) * fac);
    }
    __syncthreads();

    // ---- P3: 261 generic MLP evals (pure f32, branchless prep) ----
    if (t < NGEN) {
        int j   = t / 9;
        int i9  = t - j * 9;
        int l1m = i9 / 3;
        int l2m = i9 - l1m * 3;
        int l1  = l1m + (l1m >> 1);
        int l2  = l2m + (l2m >> 1);
        int d   = (l1 - l2) & 3;
        float v0 = sv[j][d][0], v1 = sv[j][d][1], v2 = sv[j][d][2];
        // ab = Rz(-alpha_{l2}) * v
        float ab0 = (l2m == 0) ? v0 : ((l2m == 1) ?  v1 : -v1);
        float ab1 = (l2m == 0) ? v1 : ((l2m == 1) ? -v0 :  v0);
        mlp_eval(ab0, ab1, v2, W1, b1, W2, b2, W3, b3, &swts[t][0]);
    }
    __syncthreads();

    // ---- P4: S[j][f] = valid * 0.25 * (sum_9 + G[n_j] + E[p]) ----
    for (int idx = t; idx < KNB * FCO; idx += 320) {
        int j = idx >> 4, f = idx & 15;
        float acc = 0.f;
        #pragma unroll
        for (int i9 = 0; i9 < 9; ++i9) acc += swts[j * 9 + i9][f];
        int n6 = spj[j] * 6;
        acc += eg[(n6 + 3) * FCO + f] + eg[(n6 + 4) * FCO + f] + eg[(n6 + 5) * FCO + f];
        acc += sE[f];
        sS[j][f] = sval[j] ? acc * 0.25f : 0.f;
    }
    __syncthreads();

    // ---- P5: T[b][c][f] = sum_j xv * S ----
    for (int tt = t; tt < 2 * CIN * FCO; tt += 320) {
        int bb = tt >> 9;
        int c  = (tt >> 4) & 31;
        int f  = tt & 15;
        float acc = 0.f;
        #pragma unroll
        for (int j = 0; j < KNB; ++j)
            acc += sxv[bb][c][j] * sS[j][f];
        sT[bb][c][f] = acc;
    }
    __syncthreads();

    // ---- P6: out = T @ Wl + bl (split 512-dot over 2 threads) ----
    if (t < 256) {
        int half = t >> 7, o = t & 127, bb = o >> 6, co = o & 63;
        const float* Tb = &sT[bb][0][0];
        float acc = 0.f;
        int cf0 = half * 256;
        #pragma unroll 8
        for (int cf = cf0; cf < cf0 + 256; ++cf)
            acc += Tb[cf] * Wl[cf * COUT + co];
        spp[t] = acc;
    }
    __syncthreads();
    if (t < 128) {
        int bb = t >> 6, co = t & 63;
        out[bb * (COUT * NPIX) + co * NPIX + p] = spp[t] + spp[t + 128] + bl[co];
    }
}

extern "C" void kernel_launch(void* const* d_in, const int* in_sizes, int n_in,
                              void* d_out, int out_size, void* d_ws, size_t ws_size,
                              hipStream_t stream) {
    const float* x  = (const float*)d_in[0];
    const int* nbr  = (const int*)d_in[1];
    const float* W1 = (const float*)d_in[2];
    const float* b1 = (const float*)d_in[3];
    const float* W2 = (const float*)d_in[4];
    const float* b2 = (const float*)d_in[5];
    const float* W3 = (const float*)d_in[6];
    const float* b3 = (const float*)d_in[7];
    const float* Wl = (const float*)d_in[8];
    const float* bl = (const float*)d_in[9];
    float* out = (float*)d_out;

    char* ws = (char*)d_ws;
    double* rp64 = (double*)(ws + WS_RP64);
    float*  eg   = (float*)(ws + WS_EG);
    float*  m0v  = (float*)(ws + WS_M0);

    hipLaunchKernelGGL(prep_kernel, dim3((NPIX * 6 + 1 + 255) / 256), dim3(256), 0, stream,
                       W1, b1, W2, b2, W3, b3, rp64, eg, m0v);
    hipLaunchKernelGGL(main_kernel, dim3(NPIX), dim3(320), 0, stream,
                       x, nbr, W1, b1, W2, b2, W3, b3, Wl, bl, rp64, eg, m0v, out);
}

// Round 6
// 144.793 us; speedup vs baseline: 1.2879x; 1.0845x over previous
//
#include <hip/hip_runtime.h>

#define WW   48
#define NPIX 2304
#define CIN  32
#define COUT 64
#define KNB  29
#define FCO  16
#define NPJ  (NPIX * KNB)        // 66816 (p,j) pairs
#define NT3  (NPJ * 3)           // 200448 mlp3 threads

// workspace layout (bytes); total 17,086,528
#define WS_RP64 0                // 2304*9*8      = 165888   f64 Rp
#define WS_EG   165888           // 2304*6*16*4   = 884736   edge MLP outs
#define WS_M0   1050624          // 16*4          = 64       MLP(0)
#define WS_V    1050688          // 66816*12*4    = 3207168  v_d logs (f32)
#define WS_PART 4257856          // 200448*16*4   = 12828672 partial S sums

__device__ __forceinline__ float swish_f(float x) {
    // x * sigmoid(x); rcp instead of exact-div (validated round 4, absmax unchanged)
    return x * __builtin_amdgcn_rcpf(1.0f + __expf(-x));
}

// f64 Rodrigues matching reference so3_exp
__device__ __forceinline__ void so3_exp_d(double wx, double wy, double wz, double R[9]) {
    double n  = sqrt(wx * wx + wy * wy + wz * wz);
    double th = fmax(n, 1e-7);
    double kx = wx / th, ky = wy / th, kz = wz / th;
    double s = sin(th), c = cos(th);
    double omc = 1.0 - c;
    R[0] = 1.0 + omc * (kx * kx - 1.0);
    R[1] = -s * kz + omc * kx * ky;
    R[2] =  s * ky + omc * kx * kz;
    R[3] =  s * kz + omc * kx * ky;
    R[4] = 1.0 + omc * (ky * ky - 1.0);
    R[5] = -s * kx + omc * ky * kz;
    R[6] = -s * ky + omc * kz * kx;
    R[7] =  s * kx + omc * kz * ky;
    R[8] = 1.0 + omc * (kz * kz - 1.0);
}

// f64 fisheye lift rotation Rp for pixel p (matches reference _lift_log)
__device__ __forceinline__ void compute_Rp_d(int p, double R[9]) {
    int ui = p % WW, vi = p / WW;
    double dx = (double)ui - 23.5;
    double dy = (double)vi - 23.5;
    double r  = sqrt(dx * dx + dy * dy);
    const double FOCAL = 48.0 / 3.14159265358979323846;
    double theta = r / FOCAL;
    double rs = fmax(r, 1e-7);
    double st = sin(theta);
    double rayx = st * dx / rs;
    double rayy = st * dy / rs;
    double rayz = cos(theta);
    double pz  = fmin(fmax(rayz, -1.0 + 1e-6), 1.0 - 1e-6);
    double ang = acos(pz);
    double ax = -rayy, ay = rayx;
    double an = fmax(sqrt(ax * ax + ay * ay), 1e-7);
    ax /= an; ay /= an;
    so3_exp_d(ax * ang, ay * ang, 0.0, R);
}

// streaming f32 MLP 3->32->32->16; ACCUMULATES final swish outputs into acc[16]
__device__ __forceinline__ void mlp_acc(float ab0, float ab1, float ab2,
    const float* __restrict__ W1, const float* __restrict__ b1,
    const float* __restrict__ W2, const float* __restrict__ b2,
    const float* __restrict__ W3, const float* __restrict__ b3,
    float* acc) {
    float acc2[32];
    #pragma unroll
    for (int o = 0; o < 32; ++o) acc2[o] = b2[o];
    #pragma unroll
    for (int i = 0; i < 32; ++i) {
        float h = swish_f(b1[i] + ab0 * W1[i] + ab1 * W1[32 + i] + ab2 * W1[64 + i]);
        #pragma unroll
        for (int o = 0; o < 32; ++o) acc2[o] += h * W2[i * 32 + o];
    }
    float acc3[FCO];
    #pragma unroll
    for (int f = 0; f < FCO; ++f) acc3[f] = b3[f];
    #pragma unroll
    for (int o = 0; o < 32; ++o) {
        float h = swish_f(acc2[o]);
        #pragma unroll
        for (int f = 0; f < FCO; ++f) acc3[f] += h * W3[o * FCO + f];
    }
    #pragma unroll
    for (int f = 0; f < FCO; ++f) acc[f] += swish_f(acc3[f]);
}

// ---------------- K1: per-pixel prep (Rp + edge MLP evals) ----------------
__global__ __launch_bounds__(256)
void prep_kernel(const float* __restrict__ W1, const float* __restrict__ b1,
                 const float* __restrict__ W2, const float* __restrict__ b2,
                 const float* __restrict__ W3, const float* __restrict__ b3,
                 double* __restrict__ rp64, float* __restrict__ eg,
                 float* __restrict__ m0v) {
    int g = blockIdx.x * 256 + threadIdx.x;
    if (g > NPIX * 6) return;
    if (g == NPIX * 6) {
        float o[FCO];
        #pragma unroll
        for (int f = 0; f < FCO; ++f) o[f] = 0.f;
        mlp_acc(0.f, 0.f, 0.f, W1, b1, W2, b2, W3, b3, o);
        #pragma unroll
        for (int f = 0; f < FCO; ++f) m0v[f] = o[f];
        return;
    }
    int pix = g / 6, which = g - pix * 6;
    double R[9];
    compute_Rp_d(pix, R);
    if (which == 0) {
        #pragma unroll
        for (int e = 0; e < 9; ++e) rp64[pix * 9 + e] = R[e];
    }
    int m = (which < 3) ? which : (which - 3);
    int l = m + (m >> 1);                       // 0,1,3
    double c = (l == 0) ? 1.0 : 0.0;
    double s = (l == 1) ? 1.0 : ((l == 3) ? -1.0 : 0.0);
    double M[9];
    #pragma unroll
    for (int i = 0; i < 3; ++i) {
        M[i * 3 + 0] =  R[i * 3 + 0] * c + R[i * 3 + 1] * s;
        M[i * 3 + 1] = -R[i * 3 + 0] * s + R[i * 3 + 1] * c;
        M[i * 3 + 2] =  R[i * 3 + 2];
    }
    double tr   = M[0] + M[4] + M[8];
    double cosv = fmin(fmax((tr - 1.0) * 0.5, -1.0 + 1e-6), 1.0 - 1e-6);
    double th   = acos(cosv);
    double sv   = sqrt((1.0 - cosv) * (1.0 + cosv));
    double fac  = th / (2.0 * sv);
    float sg = (which < 3) ? 1.f : -1.f;
    float o[FCO];
    #pragma unroll
    for (int f = 0; f < FCO; ++f) o[f] = 0.f;
    mlp_acc(sg * (float)((M[7] - M[5]) * fac),
            sg * (float)((M[2] - M[6]) * fac),
            sg * (float)((M[3] - M[1]) * fac),
            W1, b1, W2, b2, W3, b3, o);
    #pragma unroll
    for (int f = 0; f < FCO; ++f) eg[g * FCO + f] = o[f];
}

// ---------------- K2: per-(p,j) relative rotation + 4 logs ----------------
__global__ __launch_bounds__(256)
void vlog_kernel(const int* __restrict__ nbr, const double* __restrict__ rp64,
                 float* __restrict__ vws) {
    int tid = blockIdx.x * 256 + threadIdx.x;
    if (tid >= NPJ) return;
    int p = tid / KNB, j = tid - p * KNB;
    int idx = nbr[p * KNB + j];
    int pj = max(idx, 0);
    double Rq[9], Rn[9];
    #pragma unroll
    for (int e = 0; e < 9; ++e) Rq[e] = rp64[p * 9 + e];
    #pragma unroll
    for (int e = 0; e < 9; ++e) Rn[e] = rp64[pj * 9 + e];
    double X[9];
    #pragma unroll
    for (int i = 0; i < 3; ++i)
        #pragma unroll
        for (int jj = 0; jj < 3; ++jj) {
            double acc = 0.0;
            #pragma unroll
            for (int kk = 0; kk < 3; ++kk)
                acc += Rn[kk * 3 + i] * Rq[kk * 3 + jj];
            X[i * 3 + jj] = acc;
        }
    float* dst = vws + tid * 12;
    #pragma unroll
    for (int d = 0; d < 4; ++d) {
        double c = (d == 0) ? 1.0 : ((d == 2) ? -1.0 : 0.0);
        double s = (d == 1) ? 1.0 : ((d == 3) ? -1.0 : 0.0);
        double M0 =  X[0] * c + X[1] * s;
        double M1 = -X[0] * s + X[1] * c;
        double M2 =  X[2];
        double M3 =  X[3] * c + X[4] * s;
        double M4 = -X[3] * s + X[4] * c;
        double M5 =  X[5];
        double M6 =  X[6] * c + X[7] * s;
        double M7 = -X[6] * s + X[7] * c;
        double M8 =  X[8];
        double tr   = M0 + M4 + M8;
        double cosv = fmin(fmax((tr - 1.0) * 0.5, -1.0 + 1e-6), 1.0 - 1e-6);
        double th   = acos(cosv);
        double svv  = sqrt((1.0 - cosv) * (1.0 + cosv));
        double fac  = th / (2.0 * svv);
        dst[d * 3 + 0] = (float)((M7 - M5) * fac);
        dst[d * 3 + 1] = (float)((M2 - M6) * fac);
        dst[d * 3 + 2] = (float)((M3 - M1) * fac);
    }
}

// ---------------- K3: 3 generic MLP evals per thread (p,j,l1m) ----------------
__global__ __launch_bounds__(256, 4)
void mlp3_kernel(const float* __restrict__ W1, const float* __restrict__ b1,
                 const float* __restrict__ W2, const float* __restrict__ b2,
                 const float* __restrict__ W3, const float* __restrict__ b3,
                 const float* __restrict__ vws, float* __restrict__ part) {
    int tid = blockIdx.x * 256 + threadIdx.x;
    if (tid >= NT3) return;
    int g2  = tid / 3;            // (p,j) pair
    int l1m = tid - g2 * 3;
    int l1  = l1m + (l1m >> 1);   // 0,1,3
    const float* vp = vws + g2 * 12;
    float v[12];
    #pragma unroll
    for (int e = 0; e < 12; ++e) v[e] = vp[e];
    float acc[FCO];
    #pragma unroll
    for (int f = 0; f < FCO; ++f) acc[f] = 0.f;
    #pragma unroll
    for (int l2m = 0; l2m < 3; ++l2m) {
        int l2 = l2m + (l2m >> 1);
        int d  = (l1 - l2) & 3;
        float v0 = v[d * 3 + 0], v1 = v[d * 3 + 1], v2 = v[d * 3 + 2];
        float ab0 = (l2m == 0) ? v0 : ((l2m == 1) ?  v1 : -v1);
        float ab1 = (l2m == 0) ? v1 : ((l2m == 1) ? -v0 :  v0);
        mlp_acc(ab0, ab1, v2, W1, b1, W2, b2, W3, b3, acc);
    }
    float* dst = part + tid * FCO;
    #pragma unroll
    for (int f = 0; f < FCO; ++f) dst[f] = acc[f];
}

// ---------------- K4: per-pixel aggregation ----------------
__global__ __launch_bounds__(256)
void agg_kernel(const float* __restrict__ x, const int* __restrict__ nbr,
                const float* __restrict__ Wl, const float* __restrict__ bl,
                const float* __restrict__ eg, const float* __restrict__ m0v,
                const float* __restrict__ part, float* __restrict__ out) {
    __shared__ int   spj[KNB];
    __shared__ int   sval[KNB];
    __shared__ float sE[FCO];
    __shared__ float sS[KNB][FCO];
    __shared__ float sxv[2][CIN][KNB];
    __shared__ float sT[2][CIN][FCO];
    __shared__ float spp[256];

    const int p = blockIdx.x;
    const int t = threadIdx.x;

    // P0: neighbor indices + E vector
    if (t < KNB) {
        int idx = nbr[p * KNB + t];
        spj[t]  = max(idx, 0);
        sval[t] = (idx >= 0) ? 1 : 0;
    } else if (t >= 32 && t < 32 + FCO) {
        int f = t - 32;
        sE[f] = eg[(p * 6 + 0) * FCO + f] + eg[(p * 6 + 1) * FCO + f]
              + eg[(p * 6 + 2) * FCO + f] + m0v[f];
    }
    __syncthreads();

    // P1: stage x + build S
    for (int e = t; e < 2 * CIN * KNB; e += 256) {
        int bb = e / (CIN * KNB);
        int r  = e - bb * (CIN * KNB);
        int c  = r / KNB;
        int j  = r - c * KNB;
        sxv[bb][c][j] = x[bb * (CIN * NPIX) + c * NPIX + spj[j]];
    }
    for (int idx = t; idx < KNB * FCO; idx += 256) {
        int j = idx >> 4, f = idx & 15;
        int base = (p * KNB + j) * 3;
        float acc = part[(base + 0) * FCO + f] + part[(base + 1) * FCO + f]
                  + part[(base + 2) * FCO + f];
        int n6 = spj[j] * 6;
        acc += eg[(n6 + 3) * FCO + f] + eg[(n6 + 4) * FCO + f] + eg[(n6 + 5) * FCO + f];
        acc += sE[f];
        sS[j][f] = sval[j] ? acc * 0.25f : 0.f;
    }
    __syncthreads();

    // P2: T[b][c][f] = sum_j xv * S
    for (int tt = t; tt < 2 * CIN * FCO; tt += 256) {
        int bb = tt >> 9;
        int c  = (tt >> 4) & 31;
        int f  = tt & 15;
        float acc = 0.f;
        #pragma unroll
        for (int j = 0; j < KNB; ++j)
            acc += sxv[bb][c][j] * sS[j][f];
        sT[bb][c][f] = acc;
    }
    __syncthreads();

    // P3: out = T @ Wl + bl (512-dot split over 2 threads)
    {
        int half = t >> 7, o = t & 127, bb = o >> 6, co = o & 63;
        const float* Tb = &sT[bb][0][0];
        float acc = 0.f;
        int cf0 = half * 256;
        #pragma unroll 8
        for (int cf = cf0; cf < cf0 + 256; ++cf)
            acc += Tb[cf] * Wl[cf * COUT + co];
        spp[t] = acc;
    }
    __syncthreads();
    if (t < 128) {
        int bb = t >> 6, co = t & 63;
        out[bb * (COUT * NPIX) + co * NPIX + p] = spp[t] + spp[t + 128] + bl[co];
    }
}

extern "C" void kernel_launch(void* const* d_in, const int* in_sizes, int n_in,
                              void* d_out, int out_size, void* d_ws, size_t ws_size,
                              hipStream_t stream) {
    const float* x  = (const float*)d_in[0];
    const int* nbr  = (const int*)d_in[1];
    const float* W1 = (const float*)d_in[2];
    const float* b1 = (const float*)d_in[3];
    const float* W2 = (const float*)d_in[4];
    const float* b2 = (const float*)d_in[5];
    const float* W3 = (const float*)d_in[6];
    const float* b3 = (const float*)d_in[7];
    const float* Wl = (const float*)d_in[8];
    const float* bl = (const float*)d_in[9];
    float* out = (float*)d_out;

    char* ws = (char*)d_ws;
    double* rp64 = (double*)(ws + WS_RP64);
    float*  eg   = (float*)(ws + WS_EG);
    float*  m0v  = (float*)(ws + WS_M0);
    float*  vws  = (float*)(ws + WS_V);
    float*  part = (float*)(ws + WS_PART);

    hipLaunchKernelGGL(prep_kernel, dim3((NPIX * 6 + 1 + 255) / 256), dim3(256), 0, stream,
                       W1, b1, W2, b2, W3, b3, rp64, eg, m0v);
    hipLaunchKernelGGL(vlog_kernel, dim3((NPJ + 255) / 256), dim3(256), 0, stream,
                       nbr, rp64, vws);
    hipLaunchKernelGGL(mlp3_kernel, dim3((NT3 + 255) / 256), dim3(256), 0, stream,
                       W1, b1, W2, b2, W3, b3, vws, part);
    hipLaunchKernelGGL(agg_kernel, dim3(NPIX), dim3(256), 0, stream,
                       x, nbr, Wl, bl, eg, m0v, part, out);
}

// Round 7
// 130.012 us; speedup vs baseline: 1.4343x; 1.1137x over previous
//
#include <hip/hip_runtime.h>

#define WW   48
#define NPIX 2304
#define CIN  32
#define COUT 64
#define KNB  29
#define FCO  16
#define NPJ  (NPIX * KNB)        // 66816 (p,j) pairs

// workspace layout (bytes); total 8,534,080
#define WS_RP64 0                // 2304*9*8    = 165888   f64 Rp
#define WS_EG   165888           // 2304*6*16*4 = 884736   edge MLP outs
#define WS_M0   1050624          // 16*4        = 64       MLP(0)
#define WS_V    1050688          // 66816*12*4  = 3207168  v_d logs (f32)
#define WS_PART 4257856          // 66816*16*4  = 4276224  per-(p,j) 9-eval sums

__device__ __forceinline__ float swish_f(float x) {
    return x * __builtin_amdgcn_rcpf(1.0f + __expf(-x));
}

// f64 Rodrigues matching reference so3_exp
__device__ __forceinline__ void so3_exp_d(double wx, double wy, double wz, double R[9]) {
    double n  = sqrt(wx * wx + wy * wy + wz * wz);
    double th = fmax(n, 1e-7);
    double kx = wx / th, ky = wy / th, kz = wz / th;
    double s = sin(th), c = cos(th);
    double omc = 1.0 - c;
    R[0] = 1.0 + omc * (kx * kx - 1.0);
    R[1] = -s * kz + omc * kx * ky;
    R[2] =  s * ky + omc * kx * kz;
    R[3] =  s * kz + omc * kx * ky;
    R[4] = 1.0 + omc * (ky * ky - 1.0);
    R[5] = -s * kx + omc * ky * kz;
    R[6] = -s * ky + omc * kz * kx;
    R[7] =  s * kx + omc * kz * ky;
    R[8] = 1.0 + omc * (kz * kz - 1.0);
}

// f64 fisheye lift rotation Rp for pixel p (matches reference _lift_log)
__device__ __forceinline__ void compute_Rp_d(int p, double R[9]) {
    int ui = p % WW, vi = p / WW;
    double dx = (double)ui - 23.5;
    double dy = (double)vi - 23.5;
    double r  = sqrt(dx * dx + dy * dy);
    const double FOCAL = 48.0 / 3.14159265358979323846;
    double theta = r / FOCAL;
    double rs = fmax(r, 1e-7);
    double st = sin(theta);
    double rayx = st * dx / rs;
    double rayy = st * dy / rs;
    double rayz = cos(theta);
    double pz  = fmin(fmax(rayz, -1.0 + 1e-6), 1.0 - 1e-6);
    double ang = acos(pz);
    double ax = -rayy, ay = rayx;
    double an = fmax(sqrt(ax * ax + ay * ay), 1e-7);
    ax /= an; ay /= an;
    so3_exp_d(ax * ang, ay * ang, 0.0, R);
}

// streaming f32 MLP 3->32->32->16; writes final swish outputs to o[16]
__device__ __forceinline__ void mlp_eval(float ab0, float ab1, float ab2,
    const float* __restrict__ W1, const float* __restrict__ b1,
    const float* __restrict__ W2, const float* __restrict__ b2,
    const float* __restrict__ W3, const float* __restrict__ b3,
    float* o) {
    float acc2[32];
    #pragma unroll
    for (int q = 0; q < 32; ++q) acc2[q] = b2[q];
    #pragma unroll
    for (int i = 0; i < 32; ++i) {
        float h = swish_f(b1[i] + ab0 * W1[i] + ab1 * W1[32 + i] + ab2 * W1[64 + i]);
        #pragma unroll
        for (int q = 0; q < 32; ++q) acc2[q] += h * W2[i * 32 + q];
    }
    float acc3[FCO];
    #pragma unroll
    for (int f = 0; f < FCO; ++f) acc3[f] = b3[f];
    #pragma unroll
    for (int q = 0; q < 32; ++q) {
        float h = swish_f(acc2[q]);
        #pragma unroll
        for (int f = 0; f < FCO; ++f) acc3[f] += h * W3[q * FCO + f];
    }
    #pragma unroll
    for (int f = 0; f < FCO; ++f) o[f] = swish_f(acc3[f]);
}

// ---------------- K1: per-pixel prep (Rp + edge MLP evals) ----------------
__global__ __launch_bounds__(256)
void prep_kernel(const float* __restrict__ W1, const float* __restrict__ b1,
                 const float* __restrict__ W2, const float* __restrict__ b2,
                 const float* __restrict__ W3, const float* __restrict__ b3,
                 double* __restrict__ rp64, float* __restrict__ eg,
                 float* __restrict__ m0v) {
    int g = blockIdx.x * 256 + threadIdx.x;
    if (g > NPIX * 6) return;
    if (g == NPIX * 6) {
        float o[FCO];
        mlp_eval(0.f, 0.f, 0.f, W1, b1, W2, b2, W3, b3, o);
        #pragma unroll
        for (int f = 0; f < FCO; ++f) m0v[f] = o[f];
        return;
    }
    int pix = g / 6, which = g - pix * 6;
    double R[9];
    compute_Rp_d(pix, R);
    if (which == 0) {
        #pragma unroll
        for (int e = 0; e < 9; ++e) rp64[pix * 9 + e] = R[e];
    }
    int m = (which < 3) ? which : (which - 3);
    int l = m + (m >> 1);                       // 0,1,3
    double c = (l == 0) ? 1.0 : 0.0;
    double s = (l == 1) ? 1.0 : ((l == 3) ? -1.0 : 0.0);
    double M[9];
    #pragma unroll
    for (int i = 0; i < 3; ++i) {
        M[i * 3 + 0] =  R[i * 3 + 0] * c + R[i * 3 + 1] * s;
        M[i * 3 + 1] = -R[i * 3 + 0] * s + R[i * 3 + 1] * c;
        M[i * 3 + 2] =  R[i * 3 + 2];
    }
    double tr   = M[0] + M[4] + M[8];
    double cosv = fmin(fmax((tr - 1.0) * 0.5, -1.0 + 1e-6), 1.0 - 1e-6);
    double th   = acos(cosv);
    double sv   = sqrt((1.0 - cosv) * (1.0 + cosv));
    double fac  = th / (2.0 * sv);
    float sg = (which < 3) ? 1.f : -1.f;
    float o[FCO];
    mlp_eval(sg * (float)((M[7] - M[5]) * fac),
             sg * (float)((M[2] - M[6]) * fac),
             sg * (float)((M[3] - M[1]) * fac),
             W1, b1, W2, b2, W3, b3, o);
    #pragma unroll
    for (int f = 0; f < FCO; ++f) eg[g * FCO + f] = o[f];
}

// ---------------- K2: per-(p,j) relative rotation + 4 logs ----------------
__global__ __launch_bounds__(256)
void vlog_kernel(const int* __restrict__ nbr, const double* __restrict__ rp64,
                 float* __restrict__ vws) {
    int tid = blockIdx.x * 256 + threadIdx.x;
    if (tid >= NPJ) return;
    int p = tid / KNB, j = tid - p * KNB;
    int idx = nbr[p * KNB + j];
    int pj = max(idx, 0);
    double Rq[9], Rn[9];
    #pragma unroll
    for (int e = 0; e < 9; ++e) Rq[e] = rp64[p * 9 + e];
    #pragma unroll
    for (int e = 0; e < 9; ++e) Rn[e] = rp64[pj * 9 + e];
    double X[9];
    #pragma unroll
    for (int i = 0; i < 3; ++i)
        #pragma unroll
        for (int jj = 0; jj < 3; ++jj) {
            double acc = 0.0;
            #pragma unroll
            for (int kk = 0; kk < 3; ++kk)
                acc += Rn[kk * 3 + i] * Rq[kk * 3 + jj];
            X[i * 3 + jj] = acc;
        }
    float* dst = vws + tid * 12;
    #pragma unroll
    for (int d = 0; d < 4; ++d) {
        double c = (d == 0) ? 1.0 : ((d == 2) ? -1.0 : 0.0);
        double s = (d == 1) ? 1.0 : ((d == 3) ? -1.0 : 0.0);
        double M0 =  X[0] * c + X[1] * s;
        double M1 = -X[0] * s + X[1] * c;
        double M2 =  X[2];
        double M3 =  X[3] * c + X[4] * s;
        double M4 = -X[3] * s + X[4] * c;
        double M5 =  X[5];
        double M6 =  X[6] * c + X[7] * s;
        double M7 = -X[6] * s + X[7] * c;
        double M8 =  X[8];
        double tr   = M0 + M4 + M8;
        double cosv = fmin(fmax((tr - 1.0) * 0.5, -1.0 + 1e-6), 1.0 - 1e-6);
        double th   = acos(cosv);
        double svv  = sqrt((1.0 - cosv) * (1.0 + cosv));
        double fac  = th / (2.0 * svv);
        dst[d * 3 + 0] = (float)((M7 - M5) * fac);
        dst[d * 3 + 1] = (float)((M2 - M6) * fac);
        dst[d * 3 + 2] = (float)((M3 - M1) * fac);
    }
}

// ---------------- K3: ONE generic MLP eval per thread ----------------
// Wave layout: 7 (p,j) pairs per wave, 9 lanes each (lane 63 idle).
// e = lane%9 -> (l1m = e/3, l2m = e%3). In-wave shfl tree sums the 9
// eval outputs; lane e==0 writes part[(p*KNB+j)*16].
__global__ __launch_bounds__(256)
void mlp1_kernel(const float* __restrict__ W1, const float* __restrict__ b1,
                 const float* __restrict__ W2, const float* __restrict__ b2,
                 const float* __restrict__ W3, const float* __restrict__ b3,
                 const float* __restrict__ vws, float* __restrict__ part) {
    int wave = blockIdx.x * 4 + (threadIdx.x >> 6);
    int lane = threadIdx.x & 63;
    int slot = lane / 9;              // 0..7
    int e    = lane - slot * 9;       // 0..8
    int g2   = wave * 7 + slot;
    int g2c  = min(g2, NPJ - 1);
    int l1m = e / 3, l2m = e - l1m * 3;
    int l1 = l1m + (l1m >> 1);        // 0,1,3
    int l2 = l2m + (l2m >> 1);
    int d  = (l1 - l2) & 3;
    // per-thread v_d: plain indexed GLOBAL load (no register-array indexing)
    const float* vp = vws + g2c * 12 + d * 3;
    float v0 = vp[0], v1 = vp[1], v2 = vp[2];
    // ab = Rz(-alpha_{l2}) * v  (branchless)
    float ab0 = (l2m == 0) ? v0 : ((l2m == 1) ?  v1 : -v1);
    float ab1 = (l2m == 0) ? v1 : ((l2m == 1) ? -v0 :  v0);
    float o[FCO];
    mlp_eval(ab0, ab1, v2, W1, b1, W2, b2, W3, b3, o);
    // 9-lane reduction: offsets (1,2) then (3,6)
    #pragma unroll
    for (int f = 0; f < FCO; ++f) {
        float a = o[f];
        a += __shfl(a, min(lane + 1, 63)) + __shfl(a, min(lane + 2, 63));
        a += __shfl(a, min(lane + 3, 63)) + __shfl(a, min(lane + 6, 63));
        o[f] = a;
    }
    if (e == 0 && lane < 63 && g2 < NPJ) {
        float* dst = part + g2 * FCO;
        #pragma unroll
        for (int f = 0; f < FCO; ++f) dst[f] = o[f];
    }
}

// ---------------- K4: per-pixel aggregation ----------------
__global__ __launch_bounds__(256)
void agg_kernel(const float* __restrict__ x, const int* __restrict__ nbr,
                const float* __restrict__ Wl, const float* __restrict__ bl,
                const float* __restrict__ eg, const float* __restrict__ m0v,
                const float* __restrict__ part, float* __restrict__ out) {
    __shared__ int   spj[KNB];
    __shared__ int   sval[KNB];
    __shared__ float sE[FCO];
    __shared__ float sS[KNB][FCO];
    __shared__ float sxv[2][CIN][KNB];
    __shared__ float sT[2][CIN][FCO];
    __shared__ float spp[256];

    const int p = blockIdx.x;
    const int t = threadIdx.x;

    if (t < KNB) {
        int idx = nbr[p * KNB + t];
        spj[t]  = max(idx, 0);
        sval[t] = (idx >= 0) ? 1 : 0;
    } else if (t >= 32 && t < 32 + FCO) {
        int f = t - 32;
        sE[f] = eg[(p * 6 + 0) * FCO + f] + eg[(p * 6 + 1) * FCO + f]
              + eg[(p * 6 + 2) * FCO + f] + m0v[f];
    }
    __syncthreads();

    for (int e = t; e < 2 * CIN * KNB; e += 256) {
        int bb = e / (CIN * KNB);
        int r  = e - bb * (CIN * KNB);
        int c  = r / KNB;
        int j  = r - c * KNB;
        sxv[bb][c][j] = x[bb * (CIN * NPIX) + c * NPIX + spj[j]];
    }
    for (int idx = t; idx < KNB * FCO; idx += 256) {
        int j = idx >> 4, f = idx & 15;
        float acc = part[(p * KNB + j) * FCO + f];
        int n6 = spj[j] * 6;
        acc += eg[(n6 + 3) * FCO + f] + eg[(n6 + 4) * FCO + f] + eg[(n6 + 5) * FCO + f];
        acc += sE[f];
        sS[j][f] = sval[j] ? acc * 0.25f : 0.f;
    }
    __syncthreads();

    for (int tt = t; tt < 2 * CIN * FCO; tt += 256) {
        int bb = tt >> 9;
        int c  = (tt >> 4) & 31;
        int f  = tt & 15;
        float acc = 0.f;
        #pragma unroll
        for (int j = 0; j < KNB; ++j)
            acc += sxv[bb][c][j] * sS[j][f];
        sT[bb][c][f] = acc;
    }
    __syncthreads();

    {
        int half = t >> 7, q = t & 127, bb = q >> 6, co = q & 63;
        const float* Tb = &sT[bb][0][0];
        float acc = 0.f;
        int cf0 = half * 256;
        #pragma unroll 8
        for (int cf = cf0; cf < cf0 + 256; ++cf)
            acc += Tb[cf] * Wl[cf * COUT + co];
        spp[t] = acc;
    }
    __syncthreads();
    if (t < 128) {
        int bb = t >> 6, co = t & 63;
        out[bb * (COUT * NPIX) + co * NPIX + p] = spp[t] + spp[t + 128] + bl[co];
    }
}

extern "C" void kernel_launch(void* const* d_in, const int* in_sizes, int n_in,
                              void* d_out, int out_size, void* d_ws, size_t ws_size,
                              hipStream_t stream) {
    const float* x  = (const float*)d_in[0];
    const int* nbr  = (const int*)d_in[1];
    const float* W1 = (const float*)d_in[2];
    const float* b1 = (const float*)d_in[3];
    const float* W2 = (const float*)d_in[4];
    const float* b2 = (const float*)d_in[5];
    const float* W3 = (const float*)d_in[6];
    const float* b3 = (const float*)d_in[7];
    const float* Wl = (const float*)d_in[8];
    const float* bl = (const float*)d_in[9];
    float* out = (float*)d_out;

    char* ws = (char*)d_ws;
    double* rp64 = (double*)(ws + WS_RP64);
    float*  eg   = (float*)(ws + WS_EG);
    float*  m0v  = (float*)(ws + WS_M0);
    float*  vws  = (float*)(ws + WS_V);
    float*  part = (float*)(ws + WS_PART);

    hipLaunchKernelGGL(prep_kernel, dim3((NPIX * 6 + 1 + 255) / 256), dim3(256), 0, stream,
                       W1, b1, W2, b2, W3, b3, rp64, eg, m0v);
    hipLaunchKernelGGL(vlog_kernel, dim3((NPJ + 255) / 256), dim3(256), 0, stream,
                       nbr, rp64, vws);
    int waves = (NPJ + 6) / 7;                  // 9546
    int blocks = (waves + 3) / 4;               // 2387
    hipLaunchKernelGGL(mlp1_kernel, dim3(blocks), dim3(256), 0, stream,
                       W1, b1, W2, b2, W3, b3, vws, part);
    hipLaunchKernelGGL(agg_kernel, dim3(NPIX), dim3(256), 0, stream,
                       x, nbr, Wl, bl, eg, m0v, part, out);
}

// Round 8
// 92.939 us; speedup vs baseline: 2.0064x; 1.3989x over previous
//
#include <hip/hip_runtime.h>

#define WW   48
#define NPIX 2304
#define CIN  32
#define COUT 64
#define KNB  29
#define FCO  16
#define NPJ  (NPIX * KNB)        // 66816 (p,j) pairs

// workspace layout (bytes); total 8,534,080
#define WS_RP64 0                // 2304*9*8    = 165888   f64 Rp
#define WS_EG   165888           // 2304*6*16*4 = 884736   edge MLP outs
#define WS_M0   1050624          // 16*4        = 64       MLP(0)
#define WS_V    1050688          // 66816*12*4  = 3207168  v_d logs (f32)
#define WS_PART 4257856          // 66816*16*4  = 4276224  per-(p,j) 9-eval sums

__device__ __forceinline__ float swish_f(float x) {
    return x * __builtin_amdgcn_rcpf(1.0f + __expf(-x));
}

// f64 Rodrigues matching reference so3_exp
__device__ __forceinline__ void so3_exp_d(double wx, double wy, double wz, double R[9]) {
    double n  = sqrt(wx * wx + wy * wy + wz * wz);
    double th = fmax(n, 1e-7);
    double kx = wx / th, ky = wy / th, kz = wz / th;
    double s = sin(th), c = cos(th);
    double omc = 1.0 - c;
    R[0] = 1.0 + omc * (kx * kx - 1.0);
    R[1] = -s * kz + omc * kx * ky;
    R[2] =  s * ky + omc * kx * kz;
    R[3] =  s * kz + omc * kx * ky;
    R[4] = 1.0 + omc * (ky * ky - 1.0);
    R[5] = -s * kx + omc * ky * kz;
    R[6] = -s * ky + omc * kz * kx;
    R[7] =  s * kx + omc * kz * ky;
    R[8] = 1.0 + omc * (kz * kz - 1.0);
}

// f64 fisheye lift rotation Rp for pixel p (matches reference _lift_log)
__device__ __forceinline__ void compute_Rp_d(int p, double R[9]) {
    int ui = p % WW, vi = p / WW;
    double dx = (double)ui - 23.5;
    double dy = (double)vi - 23.5;
    double r  = sqrt(dx * dx + dy * dy);
    const double FOCAL = 48.0 / 3.14159265358979323846;
    double theta = r / FOCAL;
    double rs = fmax(r, 1e-7);
    double st = sin(theta);
    double rayx = st * dx / rs;
    double rayy = st * dy / rs;
    double rayz = cos(theta);
    double pz  = fmin(fmax(rayz, -1.0 + 1e-6), 1.0 - 1e-6);
    double ang = acos(pz);
    double ax = -rayy, ay = rayx;
    double an = fmax(sqrt(ax * ax + ay * ay), 1e-7);
    ax /= an; ay /= an;
    so3_exp_d(ax * ang, ay * ang, 0.0, R);
}

// One 16-column half of layer2 + its layer3 fold. Q0 must be a literal so
// all indices constant-fold. Recomputes h1 (3 FMA + swish each) to keep the
// peak live set at accq[16]+acc3[16]+temps ~= 44 VGPRs -> no AGPR shuffle.
__device__ __forceinline__ void mlp_half(float ab0, float ab1, float ab2, int Q0,
    const float* __restrict__ W1, const float* __restrict__ b1,
    const float* __restrict__ W2, const float* __restrict__ b2,
    const float* __restrict__ W3, const float* __restrict__ b3,
    float* acc3) {
    float accq[16];
    #pragma unroll
    for (int q = 0; q < 16; ++q) accq[q] = b2[Q0 + q];
    #pragma unroll
    for (int i = 0; i < 32; ++i) {
        float h = swish_f(b1[i] + ab0 * W1[i] + ab1 * W1[32 + i] + ab2 * W1[64 + i]);
        #pragma unroll
        for (int q = 0; q < 16; ++q) accq[q] += h * W2[i * 32 + Q0 + q];
    }
    #pragma unroll
    for (int q = 0; q < 16; ++q) {
        float h2 = swish_f(accq[q]);
        #pragma unroll
        for (int f = 0; f < FCO; ++f) acc3[f] += h2 * W3[(Q0 + q) * FCO + f];
    }
}

// streaming f32 MLP 3->32->32->16 in two low-pressure passes;
// summation order identical to the full-width version (bit-identical).
__device__ __forceinline__ void mlp_eval(float ab0, float ab1, float ab2,
    const float* __restrict__ W1, const float* __restrict__ b1,
    const float* __restrict__ W2, const float* __restrict__ b2,
    const float* __restrict__ W3, const float* __restrict__ b3,
    float* o) {
    float acc3[FCO];
    #pragma unroll
    for (int f = 0; f < FCO; ++f) acc3[f] = b3[f];
    mlp_half(ab0, ab1, ab2, 0,  W1, b1, W2, b2, W3, b3, acc3);
    __builtin_amdgcn_sched_barrier(0);   // keep the two passes' pressure isolated
    mlp_half(ab0, ab1, ab2, 16, W1, b1, W2, b2, W3, b3, acc3);
    #pragma unroll
    for (int f = 0; f < FCO; ++f) o[f] = swish_f(acc3[f]);
}

// ---------------- K1: per-pixel prep (Rp + edge MLP evals) ----------------
__global__ __launch_bounds__(256)
void prep_kernel(const float* __restrict__ W1, const float* __restrict__ b1,
                 const float* __restrict__ W2, const float* __restrict__ b2,
                 const float* __restrict__ W3, const float* __restrict__ b3,
                 double* __restrict__ rp64, float* __restrict__ eg,
                 float* __restrict__ m0v) {
    int g = blockIdx.x * 256 + threadIdx.x;
    if (g > NPIX * 6) return;
    if (g == NPIX * 6) {
        float o[FCO];
        mlp_eval(0.f, 0.f, 0.f, W1, b1, W2, b2, W3, b3, o);
        #pragma unroll
        for (int f = 0; f < FCO; ++f) m0v[f] = o[f];
        return;
    }
    int pix = g / 6, which = g - pix * 6;
    double R[9];
    compute_Rp_d(pix, R);
    if (which == 0) {
        #pragma unroll
        for (int e = 0; e < 9; ++e) rp64[pix * 9 + e] = R[e];
    }
    int m = (which < 3) ? which : (which - 3);
    int l = m + (m >> 1);                       // 0,1,3
    double c = (l == 0) ? 1.0 : 0.0;
    double s = (l == 1) ? 1.0 : ((l == 3) ? -1.0 : 0.0);
    double M[9];
    #pragma unroll
    for (int i = 0; i < 3; ++i) {
        M[i * 3 + 0] =  R[i * 3 + 0] * c + R[i * 3 + 1] * s;
        M[i * 3 + 1] = -R[i * 3 + 0] * s + R[i * 3 + 1] * c;
        M[i * 3 + 2] =  R[i * 3 + 2];
    }
    double tr   = M[0] + M[4] + M[8];
    double cosv = fmin(fmax((tr - 1.0) * 0.5, -1.0 + 1e-6), 1.0 - 1e-6);
    double th   = acos(cosv);
    double sv   = sqrt((1.0 - cosv) * (1.0 + cosv));
    double fac  = th / (2.0 * sv);
    float sg = (which < 3) ? 1.f : -1.f;
    float o[FCO];
    mlp_eval(sg * (float)((M[7] - M[5]) * fac),
             sg * (float)((M[2] - M[6]) * fac),
             sg * (float)((M[3] - M[1]) * fac),
             W1, b1, W2, b2, W3, b3, o);
    #pragma unroll
    for (int f = 0; f < FCO; ++f) eg[g * FCO + f] = o[f];
}

// ---------------- K2: per-(p,j) relative rotation + 4 logs ----------------
__global__ __launch_bounds__(256)
void vlog_kernel(const int* __restrict__ nbr, const double* __restrict__ rp64,
                 float* __restrict__ vws) {
    int tid = blockIdx.x * 256 + threadIdx.x;
    if (tid >= NPJ) return;
    int p = tid / KNB, j = tid - p * KNB;
    int idx = nbr[p * KNB + j];
    int pj = max(idx, 0);
    double Rq[9], Rn[9];
    #pragma unroll
    for (int e = 0; e < 9; ++e) Rq[e] = rp64[p * 9 + e];
    #pragma unroll
    for (int e = 0; e < 9; ++e) Rn[e] = rp64[pj * 9 + e];
    double X[9];
    #pragma unroll
    for (int i = 0; i < 3; ++i)
        #pragma unroll
        for (int jj = 0; jj < 3; ++jj) {
            double acc = 0.0;
            #pragma unroll
            for (int kk = 0; kk < 3; ++kk)
                acc += Rn[kk * 3 + i] * Rq[kk * 3 + jj];
            X[i * 3 + jj] = acc;
        }
    float* dst = vws + tid * 12;
    #pragma unroll
    for (int d = 0; d < 4; ++d) {
        double c = (d == 0) ? 1.0 : ((d == 2) ? -1.0 : 0.0);
        double s = (d == 1) ? 1.0 : ((d == 3) ? -1.0 : 0.0);
        double M0 =  X[0] * c + X[1] * s;
        double M1 = -X[0] * s + X[1] * c;
        double M2 =  X[2];
        double M3 =  X[3] * c + X[4] * s;
        double M4 = -X[3] * s + X[4] * c;
        double M5 =  X[5];
        double M6 =  X[6] * c + X[7] * s;
        double M7 = -X[6] * s + X[7] * c;
        double M8 =  X[8];
        double tr   = M0 + M4 + M8;
        double cosv = fmin(fmax((tr - 1.0) * 0.5, -1.0 + 1e-6), 1.0 - 1e-6);
        double th   = acos(cosv);
        double svv  = sqrt((1.0 - cosv) * (1.0 + cosv));
        double fac  = th / (2.0 * svv);
        dst[d * 3 + 0] = (float)((M7 - M5) * fac);
        dst[d * 3 + 1] = (float)((M2 - M6) * fac);
        dst[d * 3 + 2] = (float)((M3 - M1) * fac);
    }
}

// ---------------- K3: ONE generic MLP eval per thread ----------------
// Wave layout: 7 (p,j) pairs per wave, 9 lanes each (lane 63 idle).
__global__ __launch_bounds__(256)
void mlp1_kernel(const float* __restrict__ W1, const float* __restrict__ b1,
                 const float* __restrict__ W2, const float* __restrict__ b2,
                 const float* __restrict__ W3, const float* __restrict__ b3,
                 const float* __restrict__ vws, float* __restrict__ part) {
    int wave = blockIdx.x * 4 + (threadIdx.x >> 6);
    int lane = threadIdx.x & 63;
    int slot = lane / 9;              // 0..7
    int e    = lane - slot * 9;       // 0..8
    int g2   = wave * 7 + slot;
    int g2c  = min(g2, NPJ - 1);
    int l1m = e / 3, l2m = e - l1m * 3;
    int l1 = l1m + (l1m >> 1);        // 0,1,3
    int l2 = l2m + (l2m >> 1);
    int d  = (l1 - l2) & 3;
    // per-thread v_d: plain indexed GLOBAL load (no register-array indexing)
    const float* vp = vws + g2c * 12 + d * 3;
    float v0 = vp[0], v1 = vp[1], v2 = vp[2];
    // ab = Rz(-alpha_{l2}) * v  (branchless)
    float ab0 = (l2m == 0) ? v0 : ((l2m == 1) ?  v1 : -v1);
    float ab1 = (l2m == 0) ? v1 : ((l2m == 1) ? -v0 :  v0);
    float o[FCO];
    mlp_eval(ab0, ab1, v2, W1, b1, W2, b2, W3, b3, o);
    // 9-lane reduction: offsets (1,2) then (3,6)
    #pragma unroll
    for (int f = 0; f < FCO; ++f) {
        float a = o[f];
        a += __shfl(a, min(lane + 1, 63)) + __shfl(a, min(lane + 2, 63));
        a += __shfl(a, min(lane + 3, 63)) + __shfl(a, min(lane + 6, 63));
        o[f] = a;
    }
    if (e == 0 && lane < 63 && g2 < NPJ) {
        float* dst = part + g2 * FCO;
        #pragma unroll
        for (int f = 0; f < FCO; ++f) dst[f] = o[f];
    }
}

// ---------------- K4: per-pixel aggregation ----------------
__global__ __launch_bounds__(256)
void agg_kernel(const float* __restrict__ x, const int* __restrict__ nbr,
                const float* __restrict__ Wl, const float* __restrict__ bl,
                const float* __restrict__ eg, const float* __restrict__ m0v,
                const float* __restrict__ part, float* __restrict__ out) {
    __shared__ int   spj[KNB];
    __shared__ int   sval[KNB];
    __shared__ float sE[FCO];
    __shared__ float sS[KNB][FCO];
    __shared__ float sxv[2][CIN][KNB];
    __shared__ float sT[2][CIN][FCO];
    __shared__ float spp[256];

    const int p = blockIdx.x;
    const int t = threadIdx.x;

    if (t < KNB) {
        int idx = nbr[p * KNB + t];
        spj[t]  = max(idx, 0);
        sval[t] = (idx >= 0) ? 1 : 0;
    } else if (t >= 32 && t < 32 + FCO) {
        int f = t - 32;
        sE[f] = eg[(p * 6 + 0) * FCO + f] + eg[(p * 6 + 1) * FCO + f]
              + eg[(p * 6 + 2) * FCO + f] + m0v[f];
    }
    __syncthreads();

    for (int e = t; e < 2 * CIN * KNB; e += 256) {
        int bb = e / (CIN * KNB);
        int r  = e - bb * (CIN * KNB);
        int c  = r / KNB;
        int j  = r - c * KNB;
        sxv[bb][c][j] = x[bb * (CIN * NPIX) + c * NPIX + spj[j]];
    }
    for (int idx = t; idx < KNB * FCO; idx += 256) {
        int j = idx >> 4, f = idx & 15;
        float acc = part[(p * KNB + j) * FCO + f];
        int n6 = spj[j] * 6;
        acc += eg[(n6 + 3) * FCO + f] + eg[(n6 + 4) * FCO + f] + eg[(n6 + 5) * FCO + f];
        acc += sE[f];
        sS[j][f] = sval[j] ? acc * 0.25f : 0.f;
    }
    __syncthreads();

    for (int tt = t; tt < 2 * CIN * FCO; tt += 256) {
        int bb = tt >> 9;
        int c  = (tt >> 4) & 31;
        int f  = tt & 15;
        float acc = 0.f;
        #pragma unroll
        for (int j = 0; j < KNB; ++j)
            acc += sxv[bb][c][j] * sS[j][f];
        sT[bb][c][f] = acc;
    }
    __syncthreads();

    {
        int half = t >> 7, q = t & 127, bb = q >> 6, co = q & 63;
        const float* Tb = &sT[bb][0][0];
        float acc = 0.f;
        int cf0 = half * 256;
        #pragma unroll 8
        for (int cf = cf0; cf < cf0 + 256; ++cf)
            acc += Tb[cf] * Wl[cf * COUT + co];
        spp[t] = acc;
    }
    __syncthreads();
    if (t < 128) {
        int bb = t >> 6, co = t & 63;
        out[bb * (COUT * NPIX) + co * NPIX + p] = spp[t] + spp[t + 128] + bl[co];
    }
}

extern "C" void kernel_launch(void* const* d_in, const int* in_sizes, int n_in,
                              void* d_out, int out_size, void* d_ws, size_t ws_size,
                              hipStream_t stream) {
    const float* x  = (const float*)d_in[0];
    const int* nbr  = (const int*)d_in[1];
    const float* W1 = (const float*)d_in[2];
    const float* b1 = (const float*)d_in[3];
    const float* W2 = (const float*)d_in[4];
    const float* b2 = (const float*)d_in[5];
    const float* W3 = (const float*)d_in[6];
    const float* b3 = (const float*)d_in[7];
    const float* Wl = (const float*)d_in[8];
    const float* bl = (const float*)d_in[9];
    float* out = (float*)d_out;

    char* ws = (char*)d_ws;
    double* rp64 = (double*)(ws + WS_RP64);
    float*  eg   = (float*)(ws + WS_EG);
    float*  m0v  = (float*)(ws + WS_M0);
    float*  vws  = (float*)(ws + WS_V);
    float*  part = (float*)(ws + WS_PART);

    hipLaunchKernelGGL(prep_kernel, dim3((NPIX * 6 + 1 + 255) / 256), dim3(256), 0, stream,
                       W1, b1, W2, b2, W3, b3, rp64, eg, m0v);
    hipLaunchKernelGGL(vlog_kernel, dim3((NPJ + 255) / 256), dim3(256), 0, stream,
                       nbr, rp64, vws);
    int waves = (NPJ + 6) / 7;                  // 9546
    int blocks = (waves + 3) / 4;               // 2387
    hipLaunchKernelGGL(mlp1_kernel, dim3(blocks), dim3(256), 0, stream,
                       W1, b1, W2, b2, W3, b3, vws, part);
    hipLaunchKernelGGL(agg_kernel, dim3(NPIX), dim3(256), 0, stream,
                       x, nbr, Wl, bl, eg, m0v, part, out);
}